// Round 6
// baseline (211.896 us; speedup 1.0000x reference)
//
#include <hip/hip_runtime.h>
#include <math.h>

// Problem constants (from reference setup_inputs):
//   x, noise: (b=16, t=8, c=32, h=64, w=64) float32, values in [0,16)
//   epoch: int scalar
#define B_   16
#define T_   8
#define C_   32
#define HW_  4096            // h*w
#define K_   16              // value bins
#define BC_  (B_*C_)         // 512 samples per spatial element
#define P_BLK 8              // spatial positions per histogram workgroup

typedef unsigned int uint;

// Rotated-bin swizzle: spreads LDS banks across (t,lp) regions for both the
// data-dependent scatter atomics and the fixed-stride tail reads. Must be
// used identically by writer (atomic phase) and readers (pooled + tail).
__device__ __forceinline__ int rot2_(int t, int lp) { return 37 * lp + 13 * t; }

// ---------------------------------------------------------------------------
// Kernel P: pack the 8 temporal 4-bit values per (b,c,p) into one u32.
// packed[bc][p] = sum_t x[b][t][c][p] << (4t).  Reads x as float4 (coalesced),
// writes uint4 (coalesced). Block 0 also zeroes glob_hist (replaces memset;
// safe: glob_hist is only touched by k_hist_mi, which is stream-ordered after).
// ---------------------------------------------------------------------------
__global__ __launch_bounds__(256) void k_pack(const float4* __restrict__ x4,
                                              uint4* __restrict__ packed4,
                                              uint4* __restrict__ glob_hist4) {
  const int tid = threadIdx.x;
  if (blockIdx.x == 0) {                       // zero u32[8][256] = 512 uint4
    const uint4 z = make_uint4(0u, 0u, 0u, 0u);
    glob_hist4[tid] = z;
    glob_hist4[tid + 256] = z;
  }
  const int n  = blockIdx.x * 256 + tid;       // 0 .. 512*1024
  const int bc = n >> 10;                      // 0..511
  const int p4 = n & 1023;                     // float4 index within HW
  const int b  = bc >> 5;
  const int c  = bc & 31;
  uint4 acc = make_uint4(0u, 0u, 0u, 0u);
  #pragma unroll
  for (int t = 0; t < T_; ++t) {
    const float4 xv = x4[((b * T_ + t) * C_ + c) * (HW_ / 4) + p4];
    const int sh = 4 * t;
    acc.x |= ((uint)xv.x) << sh;
    acc.y |= ((uint)xv.y) << sh;
    acc.z |= ((uint)xv.z) << sh;
    acc.w |= ((uint)xv.w) << sh;
  }
  packed4[n] = acc;
}

// ---------------------------------------------------------------------------
// Kernel A: per-element joint histograms (t vs t=0) + per-element MI, and
// accumulate pooled (global) histograms via atomics.
// Grid: HW_/P_BLK = 512 blocks x 512 threads.
// LDS: u16-PACKED hist (two bins per u32; max count 512 << 2^16 so atomicAdd
// halves cannot carry): u32[8][8][128] = 32 KB + 4.1 KB logtab -> 36 KB
// -> 4 blocks/CU, 32 waves/CU (vs 2 blocks/42% occupancy at u32 counts).
// MI identity:  MI = ln(n) + ( Σ c·ln c − Σ_a r_a·ln r_a − Σ_v col_v·ln col_v ) / n
// MI tail: ONE LANE per (t,p) — 64 lanes of wave 0 in parallel, fully
// unrolled 16x16 with register column-marginal accumulation (static indexing).
// ---------------------------------------------------------------------------
__global__ __launch_bounds__(512, 8) void k_hist_mi(const uint* __restrict__ packed,
                                                    uint* __restrict__ glob_hist,
                                                    double* __restrict__ ele) {
  __shared__ uint   histw[T_][P_BLK][128];  // 32 KB (u16 pairs)
  __shared__ double logtab[513];            // 4.1 KB

  const int tid = threadIdx.x;
  const int p0  = blockIdx.x * P_BLK;

  for (int i = tid; i < T_ * P_BLK * 128; i += 512) ((uint*)histw)[i] = 0u;
  for (int i = tid; i < 513; i += 512) logtab[i] = (i > 0) ? log((double)i) : 0.0;
  __syncthreads();

  const int lp = tid & 7;    // which p within the block
  const int g  = tid >> 3;   // sample-group 0..63

  // Preload all 8 packed words (independent -> all in flight at once).
  uint w[8];
  #pragma unroll
  for (int k = 0; k < 8; ++k)
    w[k] = packed[(g + (k << 6)) * HW_ + p0 + lp];

  #pragma unroll
  for (int k = 0; k < 8; ++k) {
    const uint wk  = w[k];
    const int  a   = (int)(wk & 15u);
    const int  row = a << 4;
    {
      const int rb = ((row | a) + rot2_(0, lp)) & 255;           // t=0: joint(a,a)
      atomicAdd(&histw[0][lp][rb >> 1], 1u << ((rb & 1) << 4));
    }
    #pragma unroll
    for (int t = 1; t < T_; ++t) {
      const int v  = (int)((wk >> (4 * t)) & 15u);
      const int rb = ((row | v) + rot2_(t, lp)) & 255;
      atomicAdd(&histw[t][lp][rb >> 1], 1u << ((rb & 1) << 4));
    }
  }
  __syncthreads();

  // Pooled histograms: global joint = sum over p of per-element joints.
  for (int i = tid; i < T_ * 256; i += 512) {
    const int t = i >> 8, bin = i & 255;
    uint s = 0;
    #pragma unroll
    for (int p = 0; p < P_BLK; ++p) {
      const int rb = (bin + rot2_(t, p)) & 255;
      s += (histw[t][p][rb >> 1] >> ((rb & 1) << 4)) & 0xffffu;
    }
    atomicAdd(&glob_hist[i], s);
  }
  // (histw is read-only from here; no extra barrier needed)

  // Per-element MI: one lane per (t, p) — 64 lanes of wave 0, lane-parallel.
  if (tid < T_ * P_BLK) {
    const int t   = tid >> 3;
    const int lpp = tid & 7;
    const int rr  = rot2_(t, lpp);
    const uint* h = &histw[t][lpp][0];
    double term = 0.0;
    uint col[K_];
    #pragma unroll
    for (int v = 0; v < K_; ++v) col[v] = 0u;
    #pragma unroll
    for (int a = 0; a < K_; ++a) {
      uint r = 0;
      #pragma unroll
      for (int v = 0; v < K_; ++v) {
        const int  rb  = (((a << 4) | v) + rr) & 255;
        const uint cnt = (h[rb >> 1] >> ((rb & 1) << 4)) & 0xffffu;
        r += cnt;
        col[v] += cnt;
        term += (double)cnt * logtab[cnt];    // c·ln c  (logtab[0]=0)
      }
      term -= (double)r * logtab[r];          // r·ln r   (r ≤ 512)
    }
    #pragma unroll
    for (int v = 0; v < K_; ++v)
      term -= (double)col[v] * logtab[col[v]];  // col·ln col
    ele[t * HW_ + p0 + lpp] = logtab[512] + term * (1.0 / 512.0);  // MI
  }
}

// ---------------------------------------------------------------------------
// Kernel B: pooled (global) MI per t + prob. 32 blocks x 256 threads; each
// block redundantly computes glob[8] (cheap), then its 1024 prob entries.
// prob[t][p] = clip((ele[t][p]*glob[t])/(ele[0][p]*glob[0]) * epoch/200, 0, 1)
// prob[0][*] = 0.
// ---------------------------------------------------------------------------
__global__ __launch_bounds__(256) void k_glob_prob(const uint* __restrict__ glob_hist,
                                                   const double* __restrict__ ele,
                                                   const int* __restrict__ epoch_ptr,
                                                   float* __restrict__ prob) {
  __shared__ double part[256];
  __shared__ double glob[T_];
  const int tid = threadIdx.x;

  if (tid < 128) {                       // rows: Σ c·ln c − r·ln r
    const int t = tid >> 4, a = tid & 15;
    const uint* h = glob_hist + t * 256 + (a << 4);
    double s = 0.0, r = 0.0;
    #pragma unroll
    for (int v = 0; v < K_; ++v) {
      const double cnt = (double)h[v];
      r += cnt;
      if (cnt > 0.0) s += cnt * log(cnt);
    }
    if (r > 0.0) s -= r * log(r);
    part[tid] = s;
  } else {                               // cols: − col·ln col
    const int t = (tid - 128) >> 4, v = (tid - 128) & 15;
    const uint* h = glob_hist + t * 256 + v;
    double col = 0.0;
    #pragma unroll
    for (int a = 0; a < K_; ++a) col += (double)h[a << 4];
    part[tid] = (col > 0.0) ? -col * log(col) : 0.0;
  }
  __syncthreads();

  if (tid < T_) {
    double term = 0.0;
    #pragma unroll
    for (int i = 0; i < 16; ++i)
      term += part[tid * 16 + i] + part[128 + tid * 16 + i];
    const double n = (double)BC_ * (double)HW_;   // 2097152
    glob[tid] = log(n) + term / n;
  }
  __syncthreads();

  const double escale = (double)(*epoch_ptr) * (1.0 / 200.0);
  #pragma unroll
  for (int k = 0; k < 4; ++k) {
    const int i = blockIdx.x * 1024 + k * 256 + tid;   // < 32768
    const int t = i >> 12;
    const int p = i & (HW_ - 1);
    float pv = 0.0f;
    if (t != 0) {
      const double mi0 = ele[p] * glob[0];
      const double mit = ele[i] * glob[t];
      const double v  = (mit / mi0) * escale;
      pv = fminf(fmaxf((float)v, 0.0f), 1.0f);
    }
    prob[i] = pv;
  }
}

// ---------------------------------------------------------------------------
// Kernel C: out = (noise < prob[t][p]) ? 0 : x, where x is reconstructed from
// packed (values are exact 4-bit ints) — saves the 64MB x re-read.
// Traffic: packed 8MB (L2/L3) + noise 64MB + out 64MB.
// ---------------------------------------------------------------------------
__global__ __launch_bounds__(256) void k_mask(const uint4* __restrict__ packed4,
                                              const float4* __restrict__ n4,
                                              const float* __restrict__ prob,
                                              float4* __restrict__ o4) {
  const int i  = blockIdx.x * 256 + threadIdx.x;   // float4 index, < 4194304
  const int p4 = i & 1023;
  const int tc = i >> 10;          // (b*T + t)*C + c
  const int c  = tc & 31;
  const int bt = tc >> 5;          // b*T + t
  const int t  = bt & 7;
  const int b  = bt >> 3;
  const uint4 pk = packed4[(((b << 5) | c) << 10) | p4];
  const int sh = 4 * t;
  float4 xv;
  xv.x = (float)((pk.x >> sh) & 15u);
  xv.y = (float)((pk.y >> sh) & 15u);
  xv.z = (float)((pk.z >> sh) & 15u);
  xv.w = (float)((pk.w >> sh) & 15u);
  const float4 pr = ((const float4*)prob)[(t << 10) | p4];
  const float4 nv = n4[i];
  float4 o;
  o.x = (nv.x < pr.x) ? 0.0f : xv.x;
  o.y = (nv.y < pr.y) ? 0.0f : xv.y;
  o.z = (nv.z < pr.z) ? 0.0f : xv.z;
  o.w = (nv.w < pr.w) ? 0.0f : xv.w;
  o4[i] = o;
}

// ---------------------------------------------------------------------------
// Workspace layout:
//   [0, 8KB)                  glob_hist : u32[8][256]   (zeroed by k_pack blk 0)
//   [8KB, 8KB+8MB)            packed    : u32[512][4096]
//   [+8MB, +256KB)            ele       : f64[8][4096]
//   [+256KB, +128KB)          prob      : f32[8][4096]
// ---------------------------------------------------------------------------
extern "C" void kernel_launch(void* const* d_in, const int* in_sizes, int n_in,
                              void* d_out, int out_size, void* d_ws, size_t ws_size,
                              hipStream_t stream) {
  const float* x     = (const float*)d_in[0];
  const float* noise = (const float*)d_in[1];
  const int*   epoch = (const int*)d_in[2];
  float*       out   = (float*)d_out;

  char* ws = (char*)d_ws;
  uint*   glob_hist = (uint*)ws;                                         // 8 KB
  uint*   packed    = (uint*)(ws + 8192);                                // 8 MB
  double* ele       = (double*)(ws + 8192 + (size_t)BC_ * HW_ * 4);      // 256 KB
  float*  prob      = (float*)((char*)ele + (size_t)T_ * HW_ * 8);       // 128 KB

  k_pack<<<(BC_ * HW_ / 4) / 256, 256, 0, stream>>>((const float4*)x,
                                                    (uint4*)packed,
                                                    (uint4*)glob_hist);
  k_hist_mi<<<HW_ / P_BLK, 512, 0, stream>>>(packed, glob_hist, ele);
  k_glob_prob<<<32, 256, 0, stream>>>(glob_hist, ele, epoch, prob);

  const int n4 = (B_ * T_ * C_ * HW_) / 4;             // 4194304
  k_mask<<<n4 / 256, 256, 0, stream>>>((const uint4*)packed,
                                       (const float4*)noise,
                                       prob, (float4*)out);
}